// Round 9
// baseline (153.507 us; speedup 1.0000x reference)
//
#include <hip/hip_runtime.h>
#include <stdint.h>

constexpr int L_LEVELS = 16;
constexpr int T_SIZE   = 16384;
constexpr int N_PTS    = 262144;

typedef _Float16 h2 __attribute__((ext_vector_type(2)));
typedef _Float16 h4 __attribute__((ext_vector_type(4)));
typedef _Float16 h8 __attribute__((ext_vector_type(8)));

// Byte-offset-scaled hash constants: prime*4 mod 2^32, mask (T-1)*4.
constexpr uint32_t P1_4 = 2654435761u * 4u;
constexpr uint32_t P2_4 = 805459861u * 4u;
constexpr uint32_t M4   = (T_SIZE - 1) * 4u;   // 65532

__device__ __forceinline__ h2 lerp2(h2 a, h2 b, h2 t) {
    return a + t * (b - a);                     // v_pk_sub + v_pk_fma
}

// ---------------------------------------------------------------------------
// Kernel C: one-time emb f32 (L,T,2) -> fp16 (L,T) h2 copy into d_ws.
// ---------------------------------------------------------------------------
__global__ __launch_bounds__(256) void cvt_emb(
    const float4* __restrict__ src, h4* __restrict__ dst)
{
    const int i = blockIdx.x * 256 + threadIdx.x;       // 0..131071
    const float4 v = src[i];
    h4 w = { (_Float16)v.x, (_Float16)v.y, (_Float16)v.z, (_Float16)v.w };
    dst[i] = w;
}

// ---------------------------------------------------------------------------
// Main kernel: block = 1024 points x ALL 16 levels; grid = 256 = 1 block/CU.
// Per level: stage the 64 KB fp16 table into LDS (next level's slice is
// prefetched into registers during the current level's compute, so the L2
// latency hides), gather 8 corners per point, lerp, keep h2 result in regs.
// After the level loop each thread writes its point's 16 float2 = 128 B of
// lane-private contiguous output (full 64 B lines, same XCD -> no write
// amplification, no transpose kernel, no ws round-trip).
// ---------------------------------------------------------------------------
__global__ __launch_bounds__(1024, 4) void hash_encode_alllevels(
    const float* __restrict__ x,
    const h2* __restrict__ emb16,
    float4* __restrict__ out4)
{
    __shared__ float4 tabraw[T_SIZE / 2];       // 64 KB, float4 staging view
    const char* __restrict__ tb = reinterpret_cast<const char*>(tabraw);

    const int t = threadIdx.x;                  // 0..1023
    const int n = blockIdx.x * 1024 + t;        // this thread's point

    // ---- x once (3 dwords, wave touches 768 B contiguous) -----------------
    const float xv0 = x[3 * n + 0];
    const float xv1 = x[3 * n + 1];
    const float xv2 = x[3 * n + 2];

    // ---- stage level 0 -----------------------------------------------------
    float4 pf[4];
    {
        const float4* __restrict__ s4 =
            reinterpret_cast<const float4*>(emb16);
#pragma unroll
        for (int j = 0; j < 4; ++j) pf[j] = s4[j * 1024 + t];
#pragma unroll
        for (int j = 0; j < 4; ++j) tabraw[j * 1024 + t] = pf[j];
    }
    __syncthreads();

    h2 res[L_LEVELS];

#pragma unroll
    for (int l = 0; l < L_LEVELS; ++l) {
        // Prefetch next level's table slice into regs; completes during the
        // gather/lerp work below, so the post-barrier ds_write stalls little.
        if (l < L_LEVELS - 1) {
            const float4* __restrict__ s4 = reinterpret_cast<const float4*>(
                emb16 + (size_t)(l + 1) * T_SIZE);
#pragma unroll
            for (int j = 0; j < 4; ++j) pf[j] = s4[j * 1024 + t];
        }

        // N_l = 16 * 2^(5l/16); constant-folds per unrolled iteration.
        const float Nl = 16.0f * exp2f((float)l * 0.3125f);

        const float u0 = xv0 * Nl, u1 = xv1 * Nl, u2 = xv2 * Nl;
        // u >= 0: df = u - floor(u); exact-integer case gives df=0 which
        // zeroes the (possibly wrong-slot) hi-corner lerp term -> correct.
        const float fl0 = floorf(u0), fl1 = floorf(u1), fl2 = floorf(u2);
        const float df0 = u0 - fl0, df1 = u1 - fl1, df2 = u2 - fl2;

        // Byte-offset hash products for the lo corner (prime*4, wrapping).
        const uint32_t q0 = ((uint32_t)(int32_t)fl0) << 2;       // prime 1
        const uint32_t q1 = ((uint32_t)(int32_t)fl1) * P1_4;
        const uint32_t q2 = ((uint32_t)(int32_t)fl2) * P2_4;
        const uint32_t d0 = (q0 ^ (q0 + 4u))   & M4;
        const uint32_t d1 = (q1 ^ (q1 + P1_4)) & M4;
        const uint32_t d2 = (q2 ^ (q2 + P2_4)) & M4;

        uint32_t off = (q0 ^ q1 ^ q2) & M4;     // corner 000 byte offset

        // Gray-code gather order: one XOR per subsequent corner address.
        constexpr int gray[8] = {0, 1, 3, 2, 6, 7, 5, 4};
        h2 f[8];
#pragma unroll
        for (int j = 0; j < 8; ++j) {
            f[gray[j]] = *reinterpret_cast<const h2*>(tb + off);  // ds_read_b32
            if (j < 7) {
                const int tog = gray[j] ^ gray[j + 1];            // 1,2 or 4
                off ^= (tog == 4) ? d0 : (tog == 2) ? d1 : d2;
            }
        }

        // Packed-fp16 trilinear lerp tree (both features per register).
        const _Float16 h0 = (_Float16)df0, h1 = (_Float16)df1, hz = (_Float16)df2;
        const h2 t0 = {h0, h0}, t1 = {h1, h1}, t2 = {hz, hz};
        h2 e0 = lerp2(f[0], f[1], t2);
        h2 e1 = lerp2(f[2], f[3], t2);
        h2 e2 = lerp2(f[4], f[5], t2);
        h2 e3 = lerp2(f[6], f[7], t2);
        h2 g0 = lerp2(e0, e1, t1);
        h2 g1 = lerp2(e2, e3, t1);
        res[l] = lerp2(g0, g1, t0);

        __syncthreads();                        // all gathers of level l done
        if (l < L_LEVELS - 1) {
#pragma unroll
            for (int j = 0; j < 4; ++j) tabraw[j * 1024 + t] = pf[j];
            __syncthreads();                    // table l+1 ready
        }
    }

    // ---- store: 16 h2 -> 8 float4, lane-private contiguous 128 B ----------
    float4* __restrict__ dst = out4 + (size_t)n * 8;
#pragma unroll
    for (int k = 0; k < 8; ++k) {
        const h2 a = res[2 * k], b = res[2 * k + 1];
        dst[k] = make_float4((float)a.x, (float)a.y, (float)b.x, (float)b.y);
    }
}

// ---------------------------------------------------------------------------
// Fallback (ws too small for even the 1 MB table copy): round-5-style
// single-level blocks, in-kernel f32->fp16 staging, strided direct stores.
// ---------------------------------------------------------------------------
__global__ __launch_bounds__(512, 4) void hash_encode_direct(
    const float* __restrict__ x,
    const float* __restrict__ emb,
    float2* __restrict__ out)
{
    __shared__ h2 tab[T_SIZE];

    const int l     = blockIdx.x & (L_LEVELS - 1);
    const int chunk = blockIdx.x >> 4;
    const int t     = threadIdx.x;
    const int n0    = chunk * 4096 + t * 8;

    {
        const float4* __restrict__ src =
            reinterpret_cast<const float4*>(emb + (size_t)l * T_SIZE * 2);
        h8* __restrict__ d8 = reinterpret_cast<h8*>(tab);
#pragma unroll
        for (int it = 0; it < 8; ++it) {
            const int i = it * 512 + t;
            float4 a = src[2 * i];
            float4 b = src[2 * i + 1];
            h8 w = { (_Float16)a.x, (_Float16)a.y, (_Float16)a.z, (_Float16)a.w,
                     (_Float16)b.x, (_Float16)b.y, (_Float16)b.z, (_Float16)b.w };
            d8[i] = w;
        }
    }
    union { float4 q[6]; float f[24]; } xs;
    {
        const float4* __restrict__ xv =
            reinterpret_cast<const float4*>(x + (size_t)n0 * 3);
#pragma unroll
        for (int i = 0; i < 6; ++i) xs.q[i] = xv[i];
    }
    __syncthreads();

    const float Nl = 16.0f * exp2f((float)l * 0.3125f);
    const char* __restrict__ tb = reinterpret_cast<const char*>(tab);

#pragma unroll
    for (int p = 0; p < 8; ++p) {
        const float u0 = xs.f[3 * p + 0] * Nl;
        const float u1 = xs.f[3 * p + 1] * Nl;
        const float u2 = xs.f[3 * p + 2] * Nl;
        const float fl0 = floorf(u0), fl1 = floorf(u1), fl2 = floorf(u2);
        const float df0 = u0 - fl0, df1 = u1 - fl1, df2 = u2 - fl2;
        const uint32_t q0 = ((uint32_t)(int32_t)fl0) << 2;
        const uint32_t q1 = ((uint32_t)(int32_t)fl1) * P1_4;
        const uint32_t q2 = ((uint32_t)(int32_t)fl2) * P2_4;
        const uint32_t d0 = (q0 ^ (q0 + 4u))   & M4;
        const uint32_t d1 = (q1 ^ (q1 + P1_4)) & M4;
        const uint32_t d2 = (q2 ^ (q2 + P2_4)) & M4;
        uint32_t off = (q0 ^ q1 ^ q2) & M4;
        constexpr int gray[8] = {0, 1, 3, 2, 6, 7, 5, 4};
        h2 f[8];
#pragma unroll
        for (int j = 0; j < 8; ++j) {
            f[gray[j]] = *reinterpret_cast<const h2*>(tb + off);
            if (j < 7) {
                const int tog = gray[j] ^ gray[j + 1];
                off ^= (tog == 4) ? d0 : (tog == 2) ? d1 : d2;
            }
        }
        const _Float16 h0 = (_Float16)df0, h1 = (_Float16)df1, hz = (_Float16)df2;
        const h2 t0 = {h0, h0}, t1 = {h1, h1}, t2 = {hz, hz};
        h2 e0 = lerp2(f[0], f[1], t2);
        h2 e1 = lerp2(f[2], f[3], t2);
        h2 e2 = lerp2(f[4], f[5], t2);
        h2 e3 = lerp2(f[6], f[7], t2);
        h2 g0 = lerp2(e0, e1, t1);
        h2 g1 = lerp2(e2, e3, t1);
        h2 r  = lerp2(g0, g1, t0);
        out[(size_t)(n0 + p) * L_LEVELS + l] =
            make_float2((float)r.x, (float)r.y);
    }
}

extern "C" void kernel_launch(void* const* d_in, const int* in_sizes, int n_in,
                              void* d_out, int out_size, void* d_ws, size_t ws_size,
                              hipStream_t stream) {
    const float* x   = (const float*)d_in[0];
    const float* emb = (const float*)d_in[1];

    const size_t emb16_bytes = (size_t)L_LEVELS * T_SIZE * sizeof(h2); // 1 MiB

    if (ws_size >= emb16_bytes) {
        h2* emb16 = (h2*)d_ws;
        cvt_emb<<<512, 256, 0, stream>>>((const float4*)emb, (h4*)emb16);
        hash_encode_alllevels<<<256, 1024, 0, stream>>>(x, emb16,
                                                        (float4*)d_out);
    } else {
        hash_encode_direct<<<1024, 512, 0, stream>>>(x, emb, (float2*)d_out);
    }
}

// Round 10
// 87.213 us; speedup vs baseline: 1.7601x; 1.7601x over previous
//
#include <hip/hip_runtime.h>
#include <stdint.h>

constexpr int L_LEVELS = 16;
constexpr int T_SIZE   = 16384;
constexpr int N_PTS    = 262144;

typedef _Float16 h2 __attribute__((ext_vector_type(2)));
typedef _Float16 h8 __attribute__((ext_vector_type(8)));

// Byte-offset-scaled hash constants: prime*4 mod 2^32, mask (T-1)*4.
constexpr uint32_t P1_4 = 2654435761u * 4u;
constexpr uint32_t P2_4 = 805459861u * 4u;
constexpr uint32_t M4   = (T_SIZE - 1) * 4u;   // 65532

__device__ __forceinline__ h2 lerp2(h2 a, h2 b, h2 t) {
    return a + t * (b - a);                     // v_pk_sub + v_pk_fma
}

// ---------------------------------------------------------------------------
// Kernel A: block = (level, chunk of 4096 points), 512 threads.
// Each thread owns 8 CONSECUTIVE points: x arrives as 6 float4 loads (96 B
// contiguous), results leave as 2 dwordx4 stores. Level table in LDS as
// half2 (64 KB -> 2 blocks/CU). Gray-code XOR corner addressing, packed
// fp16 lerp tree. (Proven-best round-5 structure: A is LDS-random-gather
// pipe bound; VALU/VMEM/occupancy knobs were all measured neutral.)
// ---------------------------------------------------------------------------
template <bool DIRECT>
__global__ __launch_bounds__(512, 4) void hash_encode_lds(
    const float* __restrict__ x,
    const float* __restrict__ emb,
    void* __restrict__ dst_raw)
{
    __shared__ h2 tab[T_SIZE];                  // 64 KB

    const int l     = blockIdx.x & (L_LEVELS - 1);
    const int chunk = blockIdx.x >> 4;          // 0..63
    const int t     = threadIdx.x;              // 0..511
    const int n0    = chunk * 4096 + t * 8;     // first of 8 consecutive points

    // ---- stage table: 16384 half2 entries, 16 B (4 entries) per thread/iter
    {
        const float4* __restrict__ src =
            reinterpret_cast<const float4*>(emb + (size_t)l * T_SIZE * 2);
        h8* __restrict__ d8 = reinterpret_cast<h8*>(tab);
#pragma unroll
        for (int it = 0; it < 8; ++it) {
            const int i = it * 512 + t;         // < 4096
            float4 a = src[2 * i];
            float4 b = src[2 * i + 1];
            h8 w = { (_Float16)a.x, (_Float16)a.y, (_Float16)a.z, (_Float16)a.w,
                     (_Float16)b.x, (_Float16)b.y, (_Float16)b.z, (_Float16)b.w };
            d8[i] = w;                          // ds_write_b128, conflict-free
        }
    }

    // ---- prefetch this thread's 8 points (24 floats = 6 float4, aligned) ---
    union { float4 q[6]; float f[24]; } xs;
    {
        const float4* __restrict__ xv =
            reinterpret_cast<const float4*>(x + (size_t)n0 * 3);
#pragma unroll
        for (int i = 0; i < 6; ++i) xs.q[i] = xv[i];
    }

    __syncthreads();

    // N_l = 16 * 2^(5l/16); l*0.3125f exact.
    const float Nl = 16.0f * exp2f((float)l * 0.3125f);
    const char* __restrict__ tb = reinterpret_cast<const char*>(tab);

    union { h2 r[8]; float4 q[2]; } res;

#pragma unroll
    for (int p = 0; p < 8; ++p) {
        const float u0 = xs.f[3 * p + 0] * Nl;
        const float u1 = xs.f[3 * p + 1] * Nl;
        const float u2 = xs.f[3 * p + 2] * Nl;

        // u >= 0: df = u - floor(u); exact-integer case gives df=0 which
        // zeroes the (possibly wrong-slot) hi-corner lerp term -> correct.
        const float fl0 = floorf(u0), fl1 = floorf(u1), fl2 = floorf(u2);
        const float df0 = u0 - fl0, df1 = u1 - fl1, df2 = u2 - fl2;

        // Byte-offset hash products for the lo corner (prime*4, wrapping).
        const uint32_t q0 = ((uint32_t)(int32_t)fl0) << 2;       // prime 1
        const uint32_t q1 = ((uint32_t)(int32_t)fl1) * P1_4;
        const uint32_t q2 = ((uint32_t)(int32_t)fl2) * P2_4;
        // Masked XOR deltas per dim ((a^b)&M4; <<2 / mul distribute mod 2^32)
        const uint32_t d0 = (q0 ^ (q0 + 4u))   & M4;
        const uint32_t d1 = (q1 ^ (q1 + P1_4)) & M4;
        const uint32_t d2 = (q2 ^ (q2 + P2_4)) & M4;

        uint32_t off = (q0 ^ q1 ^ q2) & M4;     // corner 000 byte offset

        // Gray-code gather order: one XOR per subsequent corner address.
        constexpr int gray[8] = {0, 1, 3, 2, 6, 7, 5, 4};
        h2 f[8];
#pragma unroll
        for (int j = 0; j < 8; ++j) {
            f[gray[j]] = *reinterpret_cast<const h2*>(tb + off);  // ds_read_b32
            if (j < 7) {
                const int tog = gray[j] ^ gray[j + 1];            // 1,2 or 4
                off ^= (tog == 4) ? d0 : (tog == 2) ? d1 : d2;
            }
        }

        // Packed-fp16 trilinear lerp tree (both features per register).
        const _Float16 h0 = (_Float16)df0, h1 = (_Float16)df1, hv2 = (_Float16)df2;
        const h2 t0 = {h0, h0}, t1 = {h1, h1}, t2 = {hv2, hv2};
        h2 e0 = lerp2(f[0], f[1], t2);
        h2 e1 = lerp2(f[2], f[3], t2);
        h2 e2 = lerp2(f[4], f[5], t2);
        h2 e3 = lerp2(f[6], f[7], t2);
        h2 g0 = lerp2(e0, e1, t1);
        h2 g1 = lerp2(e2, e3, t1);
        res.r[p] = lerp2(g0, g1, t0);
    }

    if (DIRECT) {
        float2* out = reinterpret_cast<float2*>(dst_raw);
#pragma unroll
        for (int p = 0; p < 8; ++p)
            out[(size_t)(n0 + p) * L_LEVELS + l] =
                make_float2((float)res.r[p].x, (float)res.r[p].y);
    } else {
        // ws[l*N + n0 .. n0+7] as half2: 32 B contiguous -> 2 dwordx4 stores.
        float4* ws4 = reinterpret_cast<float4*>(
            reinterpret_cast<h2*>(dst_raw) + (size_t)l * N_PTS + n0);
        ws4[0] = res.q[0];
        ws4[1] = res.q[1];
    }
}

// ---------------------------------------------------------------------------
// Kernel B: transpose ws (L, N) half2 -> out (N, L) float2 via LDS tile.
// All global accesses wave-contiguous (rounds 8/9 proved partial-line
// stores suffer 4-7x HBM write amplification on gfx950).
// ---------------------------------------------------------------------------
__global__ __launch_bounds__(256) void transpose_lnf_nlf(
    const h2* __restrict__ ws,
    float2* __restrict__ out)
{
    __shared__ h2 tile[L_LEVELS][257];
    const int t    = threadIdx.x;
    const int base = blockIdx.x * 256;

#pragma unroll
    for (int l = 0; l < L_LEVELS; ++l)
        tile[l][t] = ws[(size_t)l * N_PTS + base + t];   // coalesced 4 B/lane
    __syncthreads();

#pragma unroll
    for (int i = 0; i < L_LEVELS; ++i) {
        const int flat = i * 256 + t;                    // p*16 + l
        const int p = flat >> 4;
        const int l = flat & 15;
        h2 v = tile[l][p];
        out[(size_t)base * L_LEVELS + flat] =
            make_float2((float)v.x, (float)v.y);         // coalesced 8 B/lane
    }
}

extern "C" void kernel_launch(void* const* d_in, const int* in_sizes, int n_in,
                              void* d_out, int out_size, void* d_ws, size_t ws_size,
                              hipStream_t stream) {
    const float* x   = (const float*)d_in[0];
    const float* emb = (const float*)d_in[1];

    const size_t ws_needed = (size_t)N_PTS * L_LEVELS * sizeof(h2); // 16 MiB

    if (ws_size >= ws_needed) {
        hash_encode_lds<false><<<1024, 512, 0, stream>>>(x, emb, d_ws);
        transpose_lnf_nlf<<<N_PTS / 256, 256, 0, stream>>>((const h2*)d_ws,
                                                           (float2*)d_out);
    } else {
        hash_encode_lds<true><<<1024, 512, 0, stream>>>(x, emb, d_out);
    }
}